// Round 1
// baseline (282.918 us; speedup 1.0000x reference)
//
#include <hip/hip_runtime.h>

// Problem constants (B=16, C1=C2=128, H=W=80, K=3, pad=1, stride=1)
#define HH 80
#define WW 80
#define C1 128
#define C2 128
#define NB 16
#define HWSZ 6400      // 80*80
#define KKT 1152       // C1*9 (GEMM K, reordered as k' = p*128 + c)

typedef __attribute__((ext_vector_type(8))) short bf16x8;
typedef __attribute__((ext_vector_type(4))) float f32x4;

__device__ inline ushort f2bf(float f) {
  unsigned u = __float_as_uint(f);
  return (ushort)((u + 0x7FFFu + ((u >> 16) & 1u)) >> 16);
}

// packed f32x2 -> bf16x2 (RNE, identical rounding to f2bf), 1 instr for 2 elems
__device__ inline uint cvtpk(float lo, float hi) {
  uint r;
  asm("v_cvt_pk_bf16_f32 %0, %1, %2" : "=v"(r) : "v"(lo), "v"(hi));
  return r;
}
__device__ inline float bfu_lo(uint w) { return __uint_as_float(w << 16); }
__device__ inline float bfu_hi(uint w) { return __uint_as_float(w & 0xFFFF0000u); }

// async global->LDS, 16B per lane, LDS dest = uniform base + lane*16
__device__ inline void gload_lds16(const ushort* g, ushort* l) {
  __builtin_amdgcn_global_load_lds(
      (const __attribute__((address_space(1))) void*)g,
      (__attribute__((address_space(3))) void*)l, 16, 0, 0);
}

// ---------------------------------------------------------------------------
// Kernel A: transpose x (b,c,hw) f32 -> xt (b,hw,c) bf16.  64hw x 64c tiles.
// ---------------------------------------------------------------------------
__global__ __launch_bounds__(256) void xpose_kernel(const float* __restrict__ x,
                                                    ushort* __restrict__ xt) {
  const int b = blockIdx.z;
  const int c0 = blockIdx.y * 64;
  const int hw0 = blockIdx.x * 64;
  const int tid = threadIdx.x;
  const int lane = tid & 63;

  __shared__ float ts[64][65];

  #pragma unroll
  for (int it = 0; it < 16; it++) {
    int cl = (tid >> 6) + it * 4;
    ts[cl][lane] = x[((size_t)(b * C1 + c0 + cl)) * HWSZ + hw0 + lane];
  }
  __syncthreads();

  #pragma unroll
  for (int it = 0; it < 2; it++) {
    int u = tid + it * 256;
    int j = u >> 3, cg = u & 7;
    union { uint4 v; uint w[4]; } pk;
    #pragma unroll
    for (int m = 0; m < 4; m++)
      pk.w[m] = cvtpk(ts[cg * 8 + 2 * m][j], ts[cg * 8 + 2 * m + 1][j]);
    *(uint4*)(xt + ((size_t)b * HWSZ + hw0 + j) * C1 + c0 + cg * 8) = pk.v;
  }
}

// ---------------------------------------------------------------------------
// Kernel B: combined weight prep.
//  wbf  [kt][kg][ch128][j] : main weights, k' = p*128+c order (147456)
//  wobf [kt][kg][ch32][j]  : offset-conv weights padded to 32 ch (36864)
// ---------------------------------------------------------------------------
__global__ __launch_bounds__(256) void prep_kernel(const float* __restrict__ w,
                                                   const float* __restrict__ ow,
                                                   ushort* __restrict__ wbf,
                                                   ushort* __restrict__ wobf) {
  int o = blockIdx.x * 256 + threadIdx.x;        // 184320 total
  if (o < C2 * KKT) {
    int j  = o & 7;
    int ch = (o >> 3) & 127;
    int kt = o >> 12;
    int kg = (o >> 10) & 3;
    int kprime = kt * 32 + kg * 8 + j;
    int p = kprime >> 7;
    int c = kprime & 127;
    wbf[o] = f2bf(w[(size_t)ch * KKT + c * 9 + p]);
  } else if (o < C2 * KKT + 32 * KKT) {
    int o2 = o - C2 * KKT;
    int j  = o2 & 7;
    int ch = (o2 >> 3) & 31;
    int kt = o2 >> 10;
    int kg = (o2 >> 8) & 3;
    int kprime = kt * 32 + kg * 8 + j;
    int p = kprime >> 7;
    int c = kprime & 127;
    wobf[o2] = (ch < 18) ? f2bf(ow[(size_t)ch * KKT + c * 9 + p]) : (ushort)0;
  }
}

// ---------------------------------------------------------------------------
// Kernel C: offset conv via shifted-read implicit GEMM over xt (bf16 MFMA).
// BARRIER-FREE: the old s_t LDS round-trip was a per-lane identity (write
// (cg, wave*16+pl) == read (lane>>4, wave*16+(lane&15))), so the shifted
// load IS the B fragment.  Weights (2 KB/chunk, L1-resident) are loaded
// per-wave directly from global.  No LDS, no __syncthreads -> pure streaming.
// ---------------------------------------------------------------------------
__global__ __launch_bounds__(256) void offset_mfma_kernel(
    const ushort* __restrict__ xt, const ushort* __restrict__ wobf,
    const float* __restrict__ ob, float* __restrict__ offs) {
  const int bid = blockIdx.x;                    // 0..1599
  const int b = bid & 15;
  const int tile = bid >> 4;                     // 0..99
  const int h0 = (tile / 5) * 4;
  const int w0 = (tile % 5) * 16;
  const int tid = threadIdx.x;
  const int lane = tid & 63;
  const int wave = tid >> 6;
  const int q = lane >> 4, c15 = lane & 15;
  const int spos = wave * 16 + c15;

  f32x4 acc0 = {0.f, 0.f, 0.f, 0.f}, acc1 = {0.f, 0.f, 0.f, 0.f};
  const ushort* xtb = xt + (size_t)b * HWSZ * C1;

  auto shifted_load = [&](int kt) -> uint4 {
    const int p = kt >> 2, c0 = (kt & 3) << 5;
    const int row = h0 + (spos >> 4) + (p / 3) - 1;
    const int col = w0 + (spos & 15) + (p % 3) - 1;
    uint4 v = {0u, 0u, 0u, 0u};
    if ((unsigned)row < (unsigned)HH && (unsigned)col < (unsigned)WW)
      v = *(const uint4*)(xtb + ((size_t)row * WW + col) * C1 + c0 + q * 8);
    return v;
  };

  uint4 cv = shifted_load(0);

  #pragma unroll 4
  for (int kt = 0; kt < 36; ++kt) {
    uint4 nv = {0u, 0u, 0u, 0u};
    if (kt < 35) nv = shifted_load(kt + 1);

    bf16x8 a0 = *(const bf16x8*)(wobf + ((size_t)kt * 128 + q * 32 + c15) * 8);
    bf16x8 a1 = *(const bf16x8*)(wobf + ((size_t)kt * 128 + q * 32 + 16 + c15) * 8);
    union { uint4 v; bf16x8 h; } bu; bu.v = cv;
    acc0 = __builtin_amdgcn_mfma_f32_16x16x32_bf16(a0, bu.h, acc0, 0, 0, 0);
    acc1 = __builtin_amdgcn_mfma_f32_16x16x32_bf16(a1, bu.h, acc1, 0, 0, 0);

    cv = nv;
  }

  // epilogue: D col = lane&15 (pos), row = (lane>>4)*4+reg (ch)
  {
    const int ho = h0 + wave, wo = w0 + c15;
    #pragma unroll
    for (int r = 0; r < 4; r++) {
      int ch = q * 4 + r;
      if (ch < 18)
        offs[((size_t)b * 18 + ch) * HWSZ + ho * WW + wo] = acc0[r] + ob[ch];
      int ch1 = 16 + q * 4 + r;
      if (ch1 < 18)
        offs[((size_t)b * 18 + ch1) * HWSZ + ho * WW + wo] = acc1[r] + ob[ch1];
    }
  }
}

// ---------------------------------------------------------------------------
// Kernel D: fused bilinear sampling + MFMA.
// Changes vs previous version:
//  - s_t LDS round-trip removed (it was a per-lane identity): the bilinear
//    result registers ARE the MFMA B fragment.
//  - weights double-buffered in LDS, staged with global_load_lds (width 16),
//    ONE __syncthreads per K-chunk instead of two.
//  - bilinear combine is dword-wise (1-op bf16 unpack) + v_cvt_pk_bf16_f32
//    (4 instr instead of ~32 for the pack).
// ---------------------------------------------------------------------------
struct Geo { float fy0, fy1, fx0, fx1; int o00, o01, o10, o11; };

__device__ inline Geo make_geo(float4 cd) {
  Geo g;
  int y0 = (int)cd.x, x0 = (int)cd.y;
  float wy1 = cd.z, wx1 = cd.w;
  g.fy0 = ((unsigned)y0 < (unsigned)HH) ? (1.f - wy1) : 0.f;
  g.fy1 = ((unsigned)(y0 + 1) < (unsigned)HH) ? wy1 : 0.f;
  g.fx0 = ((unsigned)x0 < (unsigned)WW) ? (1.f - wx1) : 0.f;
  g.fx1 = ((unsigned)(x0 + 1) < (unsigned)WW) ? wx1 : 0.f;
  int r0 = min(max(y0, 0), HH - 1), r1 = min(max(y0 + 1, 0), HH - 1);
  int q0 = min(max(x0, 0), WW - 1), q1 = min(max(x0 + 1, 0), WW - 1);
  g.o00 = (r0 * WW + q0) * C1; g.o01 = (r0 * WW + q1) * C1;
  g.o10 = (r1 * WW + q0) * C1; g.o11 = (r1 * WW + q1) * C1;
  return g;
}

__global__ __launch_bounds__(256) void dconv_mfma_kernel(
    const ushort* __restrict__ xt, const float* __restrict__ offs,
    const ushort* __restrict__ wbf, const float* __restrict__ bias,
    float* __restrict__ out) {
  const int bid = blockIdx.x;                    // 0..1599
  const int b = bid & 15;
  const int tile = bid >> 4;                     // 0..99
  const int h0 = (tile / 5) * 4;
  const int w0 = (tile % 5) * 16;
  const int tid = threadIdx.x;
  const int lane = tid & 63;
  const int wave = tid >> 6;
  const int q = lane >> 4, c15 = lane & 15;
  const int spos = wave * 16 + c15;

  __shared__ float4 crd[9][64];                  // 9216 B
  __shared__ ushort w_buf[2][4096];              // 16 KB (double-buffered)

  // Phase A: per-(p,pos) coords
  for (int i = tid; i < 9 * 64; i += 256) {
    int p = i >> 6, pos = i & 63;
    int r = pos >> 4, cl = pos & 15;
    int ho = h0 + r, wo = w0 + cl;
    const float* obp = offs + (size_t)b * 18 * HWSZ + ho * WW + wo;
    float dy = obp[(size_t)(2 * p) * HWSZ];
    float dx = obp[(size_t)(2 * p + 1) * HWSZ];
    float py = (float)(ho - 1 + p / 3) + dy;
    float px = (float)(wo - 1 + p % 3) + dx;
    float y0f = floorf(py), x0f = floorf(px);
    crd[p][pos] = make_float4(y0f, x0f, py - y0f, px - x0f);
  }

  // stage chunk-0 weights (8 KB, linear) while phase A settles
  #pragma unroll
  for (int j = 0; j < 2; ++j)
    gload_lds16(wbf + ((size_t)(wave * 128 + j * 64 + lane)) * 8,
                &w_buf[0][(wave * 128 + j * 64) * 8]);

  __syncthreads();   // crd ready + stage-0 drained (vmcnt(0))

  f32x4 acc[8];
  #pragma unroll
  for (int mt = 0; mt < 8; mt++) acc[mt] = (f32x4){0.f, 0.f, 0.f, 0.f};

  const ushort* xtb = xt + (size_t)b * HWSZ * C1;

  // pipeline prologue: geometry + corner gathers for chunk 0
  Geo g = make_geo(crd[0][spos]);
  uint4 ca00, ca01, ca10, ca11;
  {
    const ushort* cp = xtb + q * 8;              // c0 = 0
    ca00 = *(const uint4*)(cp + g.o00);
    ca01 = *(const uint4*)(cp + g.o01);
    ca10 = *(const uint4*)(cp + g.o10);
    ca11 = *(const uint4*)(cp + g.o11);
  }

  #pragma unroll 4
  for (int kt = 0; kt < 36; ++kt) {
    const int cur = kt & 1;

    // ---- issue next chunk: weight stage into w_buf[cur^1] + corner gathers
    Geo gn = g;
    uint4 na00 = {}, na01 = {}, na10 = {}, na11 = {};
    if (kt < 35) {
      const int kn = kt + 1;
      #pragma unroll
      for (int j = 0; j < 2; ++j)
        gload_lds16(wbf + ((size_t)kn * 512 + wave * 128 + j * 64 + lane) * 8,
                    &w_buf[cur ^ 1][(wave * 128 + j * 64) * 8]);
      if ((kn & 3) == 0) gn = make_geo(crd[kn >> 2][spos]);
      const ushort* np = xtb + ((kn & 3) << 5) + q * 8;
      na00 = *(const uint4*)(np + gn.o00);
      na01 = *(const uint4*)(np + gn.o01);
      na10 = *(const uint4*)(np + gn.o10);
      na11 = *(const uint4*)(np + gn.o11);
    }

    // ---- separable bilinear combine, dword-wise; result IS the B fragment
    union { uint4 v; uint w[4]; } u00, u01, u10, u11;
    union { uint4 v; uint w[4]; bf16x8 h; } pk;
    u00.v = ca00; u01.v = ca01; u10.v = ca10; u11.v = ca11;
    #pragma unroll
    for (int jw = 0; jw < 4; ++jw) {
      float tl = g.fx0 * bfu_lo(u00.w[jw]) + g.fx1 * bfu_lo(u01.w[jw]);
      float th = g.fx0 * bfu_hi(u00.w[jw]) + g.fx1 * bfu_hi(u01.w[jw]);
      float bl = g.fx0 * bfu_lo(u10.w[jw]) + g.fx1 * bfu_lo(u11.w[jw]);
      float bh = g.fx0 * bfu_hi(u10.w[jw]) + g.fx1 * bfu_hi(u11.w[jw]);
      float ol = g.fy0 * tl + g.fy1 * bl;
      float oh = g.fy0 * th + g.fy1 * bh;
      pk.w[jw] = cvtpk(ol, oh);
    }

    // ---- MFMA: B frag from registers, 8 A frags (128 ch) from w_buf[cur]
    #pragma unroll
    for (int mt = 0; mt < 8; mt++) {
      bf16x8 afrag = *(const bf16x8*)&w_buf[cur][(q * 128 + mt * 16 + c15) * 8];
      acc[mt] = __builtin_amdgcn_mfma_f32_16x16x32_bf16(afrag, pk.h, acc[mt], 0, 0, 0);
    }

    // one barrier per chunk: my afrag reads are retired (lgkmcnt before MFMA),
    // and the vmcnt(0) drain lands this iter's stage into w_buf[cur^1].
    __syncthreads();

    // ---- rotate pipeline registers
    g = gn;
    ca00 = na00; ca01 = na01; ca10 = na10; ca11 = na11;
  }

  // ---- epilogue
  {
    const int ho = h0 + wave, wo = w0 + c15;
    #pragma unroll
    for (int mt = 0; mt < 8; mt++) {
      #pragma unroll
      for (int r = 0; r < 4; r++) {
        int ch = mt * 16 + q * 4 + r;
        out[((size_t)b * C2 + ch) * HWSZ + ho * WW + wo] = acc[mt][r] + bias[ch];
      }
    }
  }
}

// ---------------------------------------------------------------------------
extern "C" void kernel_launch(void* const* d_in, const int* in_sizes, int n_in,
                              void* d_out, int out_size, void* d_ws, size_t ws_size,
                              hipStream_t stream) {
  const float* x    = (const float*)d_in[0];   // (16,128,80,80)
  const float* ow   = (const float*)d_in[1];   // (18,128,3,3)
  const float* ob   = (const float*)d_in[2];   // (18,)
  const float* wgt  = (const float*)d_in[3];   // (128,128,3,3)
  const float* bias = (const float*)d_in[4];   // (128,)
  float* out = (float*)d_out;                  // (16,128,80,80)

  // workspace layout (xt first for 16B alignment)
  ushort* xt   = (ushort*)d_ws;                          // 26.2 MB
  float*  offs = (float*)((char*)d_ws + 26214400);       // 7.37 MB
  ushort* wbf  = (ushort*)((char*)d_ws + 26214400 + 7372800);           // 288 KB
  ushort* wobf = (ushort*)((char*)d_ws + 26214400 + 7372800 + 294912);  // 72 KB

  prep_kernel<<<dim3(720), dim3(256), 0, stream>>>(wgt, ow, wbf, wobf);
  xpose_kernel<<<dim3(100, 2, NB), dim3(256), 0, stream>>>(x, xt);
  offset_mfma_kernel<<<dim3(1600), dim3(256), 0, stream>>>(xt, wobf, ob, offs);
  dconv_mfma_kernel<<<dim3(1600), dim3(256), 0, stream>>>(xt, offs, wbf, bias, out);
}